// Round 2
// baseline (597.201 us; speedup 1.0000x reference)
//
#include <hip/hip_runtime.h>
#include <math.h>

#define BATCH 64
#define SLEN  480050          // 200 + 150*3199
#define TFR   3200            // frames
#define FLEN  200             // frame length
#define FSH   150             // shift
#define NBINS 128             // kept DFT bins
#define EPSF  1e-7f

// ws layout in floats
#define WS_SUM 0              // 64*32 partial sums
#define WS_MU  2048           // 64
#define WS_OR  2112           // 128  sum_l cos
#define WS_OI  2240           // 128  sum_l sin
#define WS_TAB 2368           // 200*256: [l][cos 0..127 | sin 0..127]

__global__ __launch_bounds__(256) void k_sum_partial(const float* __restrict__ x,
                                                     float* __restrict__ ws) {
    int blk = blockIdx.x;          // 64*32
    int b = blk >> 5, c = blk & 31;
    const float2* row = (const float2*)(x + (size_t)b * SLEN);
    const int n2 = SLEN / 2;       // 240025
    const int per = (n2 + 31) / 32;
    int start = c * per;
    int end = start + per; if (end > n2) end = n2;
    float s = 0.f;
    for (int i = start + threadIdx.x; i < end; i += 256) {
        float2 v = row[i];
        s += v.x + v.y;
    }
    #pragma unroll
    for (int off = 1; off < 64; off <<= 1) s += __shfl_xor(s, off);
    __shared__ float ls[4];
    int wave = threadIdx.x >> 6, lane = threadIdx.x & 63;
    if (lane == 0) ls[wave] = s;
    __syncthreads();
    if (threadIdx.x == 0)
        ws[WS_SUM + b * 32 + c] = ls[0] + ls[1] + ls[2] + ls[3];
}

__global__ __launch_bounds__(64) void k_final(float* __restrict__ ws) {
    int b = threadIdx.x;
    if (b < BATCH) {
        float s = 0.f;
        #pragma unroll
        for (int c = 0; c < 32; ++c) s += ws[WS_SUM + b * 32 + c];
        ws[WS_MU + b] = s / (float)SLEN;
    }
}

// build fused table [l][256] = [cos(n) | sin(n)] and the per-bin window sums
__global__ __launch_bounds__(256) void k_tab(const float* __restrict__ rk,
                                             const float* __restrict__ ik,
                                             float* __restrict__ ws) {
    int n = blockIdx.x;            // 0..127
    int l = threadIdx.x;           // 0..255
    float cr = 0.f, ci = 0.f;
    if (l < FLEN) {
        cr = rk[n * FLEN + l];
        ci = ik[n * FLEN + l];
        ws[WS_TAB + l * 256 + n]       = cr;
        ws[WS_TAB + l * 256 + 128 + n] = ci;
    }
    #pragma unroll
    for (int off = 1; off < 64; off <<= 1) {
        cr += __shfl_xor(cr, off);
        ci += __shfl_xor(ci, off);
    }
    __shared__ float lr[4], li[4];
    int wave = threadIdx.x >> 6, lane = threadIdx.x & 63;
    if (lane == 0) { lr[wave] = cr; li[wave] = ci; }
    __syncthreads();
    if (threadIdx.x == 0) {
        ws[WS_OR + n] = lr[0] + lr[1] + lr[2] + lr[3];
        ws[WS_OI + n] = li[0] + li[1] + li[2] + li[3];
    }
}

// main fused kernel: block = 64 frames x 128 bins, thread tile = 8 frames x 4 bins
__global__ __launch_bounds__(256, 3) void k_main(const float* __restrict__ x,
                                                 const float* __restrict__ ws,
                                                 float* __restrict__ out) {
    __shared__ float frame[64][204];   // pitch 204 floats (16B-aligned rows)

    int b  = blockIdx.y;
    int t0 = blockIdx.x * 64;
    int tid = threadIdx.x;
    const float* xb = x + (size_t)b * SLEN;

    // stage 64 raw frames: 4 threads per row, float2 copies (row base is 8B aligned)
    {
        int rt = tid >> 2, rq = tid & 3;
        const float2* src = (const float2*)(xb + (t0 + rt) * FSH);
        float2* dst = (float2*)frame[rt];
        #pragma unroll
        for (int l2 = 0; l2 < 25; ++l2)
            dst[rq + l2 * 4] = src[rq + l2 * 4];
    }
    __syncthreads();

    int nq  = tid & 31;        // bin group of 4
    int tq  = tid >> 5;        // frame group of 8
    int n0  = nq * 4;
    int tl0 = tq * 8;

    const float4* tab = (const float4*)(ws + WS_TAB);

    float ar[8][4], ai[8][4];
    #pragma unroll
    for (int tt = 0; tt < 8; ++tt)
        #pragma unroll
        for (int nn = 0; nn < 4; ++nn) { ar[tt][nn] = 0.f; ai[tt][nn] = 0.f; }

    #pragma unroll 2
    for (int l = 0; l < FLEN; l += 4) {
        float4 c[4], s[4];
        #pragma unroll
        for (int k = 0; k < 4; ++k) {
            c[k] = tab[(l + k) * 64 + nq];        // cos bins n0..n0+3
            s[k] = tab[(l + k) * 64 + 32 + nq];   // sin bins n0..n0+3
        }
        #pragma unroll
        for (int tt = 0; tt < 8; ++tt) {
            float4 f = *(const float4*)&frame[tl0 + tt][l];
            float fv[4] = { f.x, f.y, f.z, f.w };
            #pragma unroll
            for (int k = 0; k < 4; ++k) {
                ar[tt][0] = fmaf(fv[k], c[k].x, ar[tt][0]);
                ar[tt][1] = fmaf(fv[k], c[k].y, ar[tt][1]);
                ar[tt][2] = fmaf(fv[k], c[k].z, ar[tt][2]);
                ar[tt][3] = fmaf(fv[k], c[k].w, ar[tt][3]);
                ai[tt][0] = fmaf(fv[k], s[k].x, ai[tt][0]);
                ai[tt][1] = fmaf(fv[k], s[k].y, ai[tt][1]);
                ai[tt][2] = fmaf(fv[k], s[k].z, ai[tt][2]);
                ai[tt][3] = fmaf(fv[k], s[k].w, ai[tt][3]);
            }
        }
    }

    // epilogue: mean-correction (DFT linearity), magnitude, log10.
    // NOTE: the 1/(sd+eps) factor is a constant log-shift per batch and cancels
    // exactly in the per-(b,t) bin normalization below, so it is never computed.
    float mu = ws[WS_MU + b];
    float4 orv = *(const float4*)(ws + WS_OR + n0);
    float4 oiv = *(const float4*)(ws + WS_OI + n0);
    float orr[4] = { orv.x, orv.y, orv.z, orv.w };
    float oii[4] = { oiv.x, oiv.y, oiv.z, oiv.w };

    float v[8][4];
    #pragma unroll
    for (int tt = 0; tt < 8; ++tt) {
        #pragma unroll
        for (int nn = 0; nn < 4; ++nn) {
            float re = ar[tt][nn] - mu * orr[nn];
            float im = ai[tt][nn] - mu * oii[nn];
            float m = sqrtf(fmaf(re, re, im * im));
            m = fmaxf(m, EPSF);
            v[tt][nn] = __log2f(m) * 0.3010299956639812f;   // log10
        }
    }

    // per-(b,t) normalization over the 128 bins (32 lanes x 4 regs)
    #pragma unroll
    for (int tt = 0; tt < 8; ++tt) {
        float s = (v[tt][0] + v[tt][1]) + (v[tt][2] + v[tt][3]);
        float q = fmaf(v[tt][0], v[tt][0], v[tt][1] * v[tt][1])
                + fmaf(v[tt][2], v[tt][2], v[tt][3] * v[tt][3]);
        #pragma unroll
        for (int off = 1; off < 32; off <<= 1) {
            s += __shfl_xor(s, off);
            q += __shfl_xor(q, off);
        }
        float mean = s * (1.0f / 128.0f);
        float var  = q * (1.0f / 128.0f) - mean * mean;
        float sd   = sqrtf(fmaxf(var, 0.f));
        float sc   = 1.0f / (sd + EPSF);
        #pragma unroll
        for (int nn = 0; nn < 4; ++nn)
            v[tt][nn] = (v[tt][nn] - mean) * sc;
    }

    // write out[b][n][t]: two float4 per bin over 8 consecutive t
    float* ob = out + (size_t)b * NBINS * TFR + t0 + tl0;
    #pragma unroll
    for (int nn = 0; nn < 4; ++nn) {
        float* base = ob + (size_t)(n0 + nn) * TFR;
        *(float4*)(base)     = make_float4(v[0][nn], v[1][nn], v[2][nn], v[3][nn]);
        *(float4*)(base + 4) = make_float4(v[4][nn], v[5][nn], v[6][nn], v[7][nn]);
    }
}

extern "C" void kernel_launch(void* const* d_in, const int* in_sizes, int n_in,
                              void* d_out, int out_size, void* d_ws, size_t ws_size,
                              hipStream_t stream) {
    const float* x  = (const float*)d_in[0];
    const float* rk = (const float*)d_in[1];
    const float* ik = (const float*)d_in[2];
    float* out = (float*)d_out;
    float* ws  = (float*)d_ws;

    k_sum_partial<<<BATCH * 32, 256, 0, stream>>>(x, ws);
    k_final<<<1, 64, 0, stream>>>(ws);
    k_tab<<<NBINS, 256, 0, stream>>>(rk, ik, ws);
    k_main<<<dim3(TFR / 64, BATCH), 256, 0, stream>>>(x, ws, out);
}